// Round 2
// baseline (176.038 us; speedup 1.0000x reference)
//
#include <hip/hip_runtime.h>

// Problem constants (match reference: B=8192, N=2048, K=64, f32 in/out)
#define B_ROWS 8192
#define N_DIM  2048
#define K_DIM  64

// Kernel 1: s[n] = sum_k v[n,k]^2.  One wave per row, 4 rows/block.
__global__ __launch_bounds__(256) void fm_prep_s(const float* __restrict__ v,
                                                 float* __restrict__ s) {
    const int wv   = threadIdx.x >> 6;
    const int lane = threadIdx.x & 63;
    const int row  = blockIdx.x * 4 + wv;
    float val = v[(size_t)row * K_DIM + lane];   // coalesced 256B per wave
    float sq  = val * val;
    #pragma unroll
    for (int off = 1; off < 64; off <<= 1)
        sq += __shfl_xor(sq, off, 64);
    if (lane == 0) s[row] = sq;
}

// Kernel 2: fused xv-GEMM + ssum + epilogue reduction.
// Block: 512 threads = 8 waves, 16 rows of x. Wave w handles n in [w*256, w*256+256).
// Lane k accumulates column k of xv for all 16 rows (x broadcast via scalar loads).
__global__ __launch_bounds__(512, 4) void fm_main(const float* __restrict__ x,
                                                  const float* __restrict__ v,
                                                  const float* __restrict__ s,
                                                  float* __restrict__ out) {
    __shared__ float lds_acc[8][16][64];   // 32 KiB: per-wave partial xv
    __shared__ float lds_ssum[8][16];      // per-wave partial sum x^2*s per row

    const int lane = threadIdx.x & 63;
    const int wv   = __builtin_amdgcn_readfirstlane((int)(threadIdx.x >> 6));
    const int b0   = blockIdx.x * 16;
    const int ns   = wv * 256;             // wave-uniform n-slice base

    float acc[16];
    #pragma unroll
    for (int m = 0; m < 16; ++m) acc[m] = 0.f;
    float ssum = 0.f;

    // ssum lane mapping: 64 lanes = 16 rows x 4 j-groups of 4 consecutive n's
    const int ml = lane >> 2;          // row this lane covers for the x^2*s term
    const int jb = (lane & 3) * 4;     // n sub-offset within a 16-n chunk

    for (int c = 0; c < 16; ++c) {     // 16 chunks x 16 n = 256 n per wave
        const int n0 = ns + c * 16;

        // ---- x^2 * s path (per-lane vector loads, ~3% of VALU; L1-hot:
        //      same tile the GEMM path reads via the scalar cache) ----
        float4 xq = *(const float4*)(x + (size_t)(b0 + ml) * N_DIM + n0 + jb);
        float4 sq = *(const float4*)(s + n0 + jb);
        ssum = fmaf(xq.x * xq.x, sq.x, ssum);
        ssum = fmaf(xq.y * xq.y, sq.y, ssum);
        ssum = fmaf(xq.z * xq.z, sq.z, ssum);
        ssum = fmaf(xq.w * xq.w, sq.w, ssum);

        // ---- GEMM path: acc[m] (lane = column k) ----
        #pragma unroll
        for (int j0 = 0; j0 < 16; j0 += 4) {
            // v[n][lane]: uniform row base + lane*4 -> coalesced 256B loads
            float vv0 = v[(size_t)(n0 + j0 + 0) * K_DIM + lane];
            float vv1 = v[(size_t)(n0 + j0 + 1) * K_DIM + lane];
            float vv2 = v[(size_t)(n0 + j0 + 2) * K_DIM + lane];
            float vv3 = v[(size_t)(n0 + j0 + 3) * K_DIM + lane];
            #pragma unroll
            for (int m = 0; m < 16; ++m) {
                // wave-uniform address -> scalar loads (s_load_dwordx4), x in SGPRs
                float4 sx = *(const float4*)(x + (size_t)(b0 + m) * N_DIM + n0 + j0);
                acc[m] = fmaf(sx.x, vv0, acc[m]);
                acc[m] = fmaf(sx.y, vv1, acc[m]);
                acc[m] = fmaf(sx.z, vv2, acc[m]);
                acc[m] = fmaf(sx.w, vv3, acc[m]);
            }
        }
    }

    // reduce ssum across the 4 lanes that share row ml
    ssum += __shfl_xor(ssum, 1, 64);
    ssum += __shfl_xor(ssum, 2, 64);
    if ((lane & 3) == 0) lds_ssum[wv][ml] = ssum;
    #pragma unroll
    for (int m = 0; m < 16; ++m) lds_acc[wv][m][lane] = acc[m];
    __syncthreads();

    // each wave finalizes rows 2*wv and 2*wv+1
    #pragma unroll
    for (int r = 0; r < 2; ++r) {
        const int m = wv * 2 + r;
        float t = 0.f;
        #pragma unroll
        for (int w = 0; w < 8; ++w) t += lds_acc[w][m][lane];  // stride-1: conflict-free
        float q = t * t;
        #pragma unroll
        for (int off = 1; off < 64; off <<= 1)
            q += __shfl_xor(q, off, 64);
        if (lane == 0) {
            float ss = 0.f;
            #pragma unroll
            for (int w = 0; w < 8; ++w) ss += lds_ssum[w][m];
            out[b0 + m] = 0.5f * (q - ss);
        }
    }
}

extern "C" void kernel_launch(void* const* d_in, const int* in_sizes, int n_in,
                              void* d_out, int out_size, void* d_ws, size_t ws_size,
                              hipStream_t stream) {
    const float* x = (const float*)d_in[0];   // [8192, 2048] f32
    const float* v = (const float*)d_in[1];   // [2048, 64]  f32
    float* out = (float*)d_out;               // [8192, 1]   f32
    float* s   = (float*)d_ws;                // [2048] f32 scratch (recomputed every call)

    fm_prep_s<<<dim3(N_DIM / 4), dim3(256), 0, stream>>>(v, s);
    fm_main<<<dim3(B_ROWS / 16), dim3(512), 0, stream>>>(x, v, s, out);
}

// Round 6
// 108.369 us; speedup vs baseline: 1.6244x; 1.6244x over previous
//
#include <hip/hip_runtime.h>
#include <hip/hip_bf16.h>

// B=8192, N=2048 (GEMM reduce dim), K=64 (output cols), f32 in/out.
// FM identity with algebraic cut: res = 0.5*( ||x@v||^2 - sum_n x[n]^2 * s[n] ),
// s[n] = sum_k v[n,k]^2.  xv GEMM done in bf16 hi/lo split (3 MFMAs, xl*vl
// dropped: rel err ~2^-17, far below the f32 version's measured absmax 0.0039).
#define B_ROWS 8192
#define N_DIM  2048
#define K_DIM  64

using frag_ab = __attribute__((ext_vector_type(8))) short;  // 8 bf16 = 4 VGPR
using frag_cd = __attribute__((ext_vector_type(4))) float;  // 4 f32

// ---- prep 1: s[n] = sum_k v[n,k]^2 ----
__global__ __launch_bounds__(256) void fm_prep_s(const float* __restrict__ v,
                                                 float* __restrict__ s) {
    const int wv = threadIdx.x >> 6, lane = threadIdx.x & 63;
    const int row = blockIdx.x * 4 + wv;
    float val = v[(size_t)row * K_DIM + lane];
    float sq = val * val;
    #pragma unroll
    for (int off = 1; off < 64; off <<= 1) sq += __shfl_xor(sq, off, 64);
    if (lane == 0) s[row] = sq;
}

// ---- prep 2: pack v into MFMA-B fragment order, bf16 hi/lo ----
// B[k][n] fragment (16x16x32): n = lane&15, k = (lane>>4)*8 + i  (same sigma
// as the A-side x load below — any k-permutation cancels A-vs-B).
__global__ __launch_bounds__(256) void fm_pack_v(const float* __restrict__ v,
                                                 unsigned short* __restrict__ vh,
                                                 unsigned short* __restrict__ vl) {
    const int c = blockIdx.x;          // K-chunk 0..63 (k0 = 32c over N_DIM)
    const int t = threadIdx.x >> 6;    // n-tile 0..3 (16 cols each)
    const int l = threadIdx.x & 63;
    const int kb = c * 32 + ((l >> 4) << 3);
    const int n  = t * 16 + (l & 15);
    frag_ab hv, lv;
    #pragma unroll
    for (int i = 0; i < 8; ++i) {
        float f = v[(size_t)(kb + i) * K_DIM + n];
        __hip_bfloat16 h = __float2bfloat16(f);          // RNE hi
        float fh = __bfloat162float(h);
        __hip_bfloat16 r = __float2bfloat16(f - fh);     // RNE lo
        hv[i] = (short)*reinterpret_cast<unsigned short*>(&h);
        lv[i] = (short)*reinterpret_cast<unsigned short*>(&r);
    }
    const size_t off = ((size_t)(c * 4 + t) * 64 + l) * 8;
    *reinterpret_cast<frag_ab*>(vh + off) = hv;   // coalesced 16B/lane
    *reinterpret_cast<frag_ab*>(vl + off) = lv;
}

// ---- main: 16 rows/block, 8 waves, wave w reduces K-slice [w*256,(w+1)*256) ----
__global__ __launch_bounds__(512, 4) void fm_main(const float* __restrict__ x,
                                                  const float* __restrict__ s,
                                                  const unsigned short* __restrict__ vhp,
                                                  const unsigned short* __restrict__ vlp,
                                                  float* __restrict__ out) {
    __shared__ float lds_acc[8][16][65];   // pad 65: conflict-free scatter
    __shared__ float lds_ss[8][16];

    const int l   = threadIdx.x & 63;
    const int w   = __builtin_amdgcn_readfirstlane((int)(threadIdx.x >> 6));
    const int b0  = blockIdx.x * 16;
    const int row = l & 15;                // A-fragment M index
    const int kg  = l >> 4;                // lane k-group

    frag_cd acc[4];
    #pragma unroll
    for (int t = 0; t < 4; ++t) acc[t] = frag_cd{0.f, 0.f, 0.f, 0.f};
    float ssum = 0.f;

    const float* xrow = x + (size_t)(b0 + row) * N_DIM + kg * 8;
    const int c0 = w * 8;                  // global 32-k chunk base for this wave

    for (int c = 0; c < 8; ++c) {
        const int cc = c0 + c;
        const float4 xa = *(const float4*)(xrow + cc * 32);
        const float4 xb = *(const float4*)(xrow + cc * 32 + 4);
        const float4 sa = *(const float4*)(s + cc * 32 + kg * 8);
        const float4 sb = *(const float4*)(s + cc * 32 + kg * 8 + 4);
        const float xs[8] = {xa.x, xa.y, xa.z, xa.w, xb.x, xb.y, xb.z, xb.w};
        const float sv[8] = {sa.x, sa.y, sa.z, sa.w, sb.x, sb.y, sb.z, sb.w};
        frag_ab ah, al;
        #pragma unroll
        for (int i = 0; i < 8; ++i) {
            const float f = xs[i];
            __hip_bfloat16 h = __float2bfloat16(f);
            const float fh = __bfloat162float(h);
            __hip_bfloat16 r = __float2bfloat16(f - fh);
            ah[i] = (short)*reinterpret_cast<unsigned short*>(&h);
            al[i] = (short)*reinterpret_cast<unsigned short*>(&r);
            ssum = fmaf(f * f, sv[i], ssum);   // x^2*s rides the same loads
        }
        const unsigned short* ph = vhp + ((size_t)cc * 4 * 64 + l) * 8;
        const unsigned short* pl = vlp + ((size_t)cc * 4 * 64 + l) * 8;
        #pragma unroll
        for (int t = 0; t < 4; ++t) {
            const frag_ab bh = *(const frag_ab*)(ph + t * 512);
            const frag_ab bl = *(const frag_ab*)(pl + t * 512);
            acc[t] = __builtin_amdgcn_mfma_f32_16x16x32_bf16(ah, bh, acc[t], 0, 0, 0);
            acc[t] = __builtin_amdgcn_mfma_f32_16x16x32_bf16(al, bh, acc[t], 0, 0, 0);
            acc[t] = __builtin_amdgcn_mfma_f32_16x16x32_bf16(ah, bl, acc[t], 0, 0, 0);
        }
    }

    // ssum: lanes {r, r+16, r+32, r+48} hold row r partials
    ssum += __shfl_xor(ssum, 16, 64);
    ssum += __shfl_xor(ssum, 32, 64);
    if (l < 16) lds_ss[w][l] = ssum;
    // D layout (m89-verified): n = lane&15, m = (lane>>4)*4 + r
    #pragma unroll
    for (int t = 0; t < 4; ++t) {
        #pragma unroll
        for (int r = 0; r < 4; ++r)
            lds_acc[w][kg * 4 + r][t * 16 + row] = acc[t][r];
    }
    __syncthreads();

    #pragma unroll
    for (int rr = 0; rr < 2; ++rr) {
        const int m = w * 2 + rr;
        float tsum = 0.f;
        #pragma unroll
        for (int w2 = 0; w2 < 8; ++w2) tsum += lds_acc[w2][m][l];  // stride-1
        float q = tsum * tsum;
        #pragma unroll
        for (int off = 1; off < 64; off <<= 1) q += __shfl_xor(q, off, 64);
        if (l == 0) {
            float sst = 0.f;
            #pragma unroll
            for (int w2 = 0; w2 < 8; ++w2) sst += lds_ss[w2][m];
            out[b0 + m] = 0.5f * (q - sst);
        }
    }
}

extern "C" void kernel_launch(void* const* d_in, const int* in_sizes, int n_in,
                              void* d_out, int out_size, void* d_ws, size_t ws_size,
                              hipStream_t stream) {
    const float* x = (const float*)d_in[0];   // [8192, 2048] f32
    const float* v = (const float*)d_in[1];   // [2048, 64]  f32
    float* out = (float*)d_out;               // [8192] f32
    // workspace: s (8KB) | vh packed (256KB) | vl packed (256KB) = 520.5KB
    float* s = (float*)d_ws;
    unsigned short* vh = (unsigned short*)((char*)d_ws + 8192);
    unsigned short* vl = (unsigned short*)((char*)d_ws + 8192 + 262144);

    fm_prep_s<<<dim3(N_DIM / 4), dim3(256), 0, stream>>>(v, s);
    fm_pack_v<<<dim3(64), dim3(256), 0, stream>>>(v, vh, vl);
    fm_main<<<dim3(B_ROWS / 16), dim3(512), 0, stream>>>(x, s, vh, vl, out);
}